// Round 23
// baseline (828.291 us; speedup 1.0000x reference)
//
#include <hip/hip_runtime.h>
#include <hip/hip_bf16.h>

#define NB 512
#define NT 274
#define ND 256
#define NH 512
#define NHH 1024
#define NPOS (NB*NT)
#define EPSF 1e-5f
#define TILE 16
#define HALO 22
#define YST 264    // y row stride (elems); 32 rows in s_a
#define UST 520    // u/uc/v row stride

typedef float f32x4 __attribute__((ext_vector_type(4)));
typedef float f32x2 __attribute__((ext_vector_type(2)));
typedef unsigned int u32x4 __attribute__((ext_vector_type(4)));
typedef unsigned int u32x2 __attribute__((ext_vector_type(2)));
typedef short s16x8 __attribute__((ext_vector_type(8)));   // 8 bf16 = 4 VGPRs

__device__ __forceinline__ float bf2f(unsigned short s) {
    unsigned int u = ((unsigned int)s) << 16;
    float f; __builtin_memcpy(&f, &u, 4); return f;
}
__device__ __forceinline__ unsigned short f2bf(float f) {
    __hip_bfloat16 b = __float2bfloat16(f);
    unsigned short r; __builtin_memcpy(&r, &b, 2); return r;
}
__device__ __forceinline__ unsigned int f2bf2(float lo, float hi) {
    return (unsigned)f2bf(lo) | ((unsigned)f2bf(hi) << 16);
}
// unpack 2 bf16 (lo,hi) from one u32 -> f32x2 (1 shl + 1 and)
__device__ __forceinline__ f32x2 upk2(unsigned int u) {
    unsigned int lo = u << 16, hi = u & 0xffff0000u;
    float flo, fhi;
    __builtin_memcpy(&flo, &lo, 4);
    __builtin_memcpy(&fhi, &hi, 4);
    return (f32x2){flo, fhi};
}
// fast sigmoid via v_rcp_f32 (<=1e-7 rel err); output feeds bf16 -> safe
__device__ __forceinline__ float sigm(float x) {
    return __builtin_amdgcn_rcpf(1.0f + __expf(-x));
}

// ------- prep: weights -> bf16 MFMA-FRAGMENT ORDER; LN gamma folded into inw;
//         inb_f = inb + inw . lnb ; dww -> symmetrized f32 -------
__global__ __launch_bounds__(256) void k_prep(const float* __restrict__ outw,
    const float* __restrict__ mixw, const float* __restrict__ inw,
    const float* __restrict__ dww,
    const float* __restrict__ lng, const float* __restrict__ lnb,
    const float* __restrict__ inb,
    unsigned short* __restrict__ ob, unsigned short* __restrict__ mb,
    unsigned short* __restrict__ iwb, float* __restrict__ dws,
    float* __restrict__ inb_f)
{
    int i = blockIdx.x*256 + threadIdx.x;   // 0 .. 798719
    if (i < 524288) {
        // outw: per layer 256x512, instr = ks*16 + c4t
        int l = i >> 17, q = i & 131071;
        int j = q & 7, lane = (q >> 3) & 63, c4t = (q >> 9) & 15, ks = q >> 13;
        int src = (c4t*16 + (lane & 15))*512 + ks*32 + (lane >> 4)*8 + j;
        ob[i] = f2bf(outw[(size_t)l*131072 + src]);
    } else if (i < 655360) {
        // mixw: per layer 512x64, instr = (g*4+nt)*2 + half
        int v = i - 524288;
        int l = v >> 15, q = v & 32767;
        int j = q & 7, lane = (q >> 3) & 63, half = (q >> 9) & 1, gnt = q >> 10;
        int g = gnt >> 2, nt = gnt & 3;
        int src = (g*64 + nt*16 + (lane & 15))*64 + half*32 + (lane >> 4)*8 + j;
        mb[v] = f2bf(mixw[(size_t)l*32768 + src]);
    } else if (i < 786432) {
        // inw: per layer 1024x32, instr = g*8 + nt ; LN gamma folded in
        int v = i - 655360;
        int l = v >> 15, q = v & 32767;
        int j = q & 7, lane = (q >> 3) & 63, gnt = q >> 9;
        int g = gnt >> 3, nt = gnt & 7;
        int kk = (lane >> 4)*8 + j;               // k within group
        int src = (g*128 + nt*16 + (lane & 15))*32 + kk;
        float w = inw[(size_t)l*32768 + src] * lng[l*ND + g*32 + kk];
        iwb[v] = f2bf(w);
    } else if (i < 794624) {
        // dws[l][c][k] = 0.5*(dww[k] + dww[6-k]), k=0..3
        int v = i - 786432;
        int l = v >> 11, c = (v >> 2) & 511, k = v & 3;
        const float* w = dww + (size_t)l*3584 + c*7;
        dws[v] = 0.5f*(w[k] + w[6-k]);
    } else if (i < 798720) {
        // inb_f[l][c] = inb[l][c] + sum_k inw[l][c][k]*lnb[l][g*32+k]
        int v = i - 794624;
        int l = v >> 10, c = v & 1023, g = c >> 7;
        const float* wr = inw + (size_t)l*32768 + c*32;
        const float* lb = lnb + l*ND + g*32;
        float s = inb[l*NHH + c];
        #pragma unroll
        for (int k = 0; k < 32; ++k) s = fmaf(wr[k], lb[k], s);
        inb_f[v] = s;
    }
}

// ======= kL2<FIRST,LAST>: whole layer fused, 512 thr / 8 waves =======
// FIRST: h computed inline from x/w_in/b_in/pos. LAST: final LN fused.
// r23: P2 conv repartitioned to channel-pair u32 LDS ops (44 -> 22 LDS
// instrs/thread); P0 LN sums accumulated as f32x2 (packed adds).
template<bool FIRST, bool LAST>
__global__ __launch_bounds__(512, 8) void kL2(const float* __restrict__ hin,
    float* __restrict__ hout,
    const unsigned short* __restrict__ inw_b, const float* __restrict__ inb_f,
    const float* __restrict__ dws,
    const unsigned short* __restrict__ mixw_b, const float* __restrict__ mixb,
    const unsigned short* __restrict__ outw_b, const float* __restrict__ outb,
    const float* __restrict__ x, const float* __restrict__ w_in,
    const float* __restrict__ b_in, const float* __restrict__ pos,
    const float* __restrict__ olng, const float* __restrict__ olnb)
{
    const int b   = blockIdx.y;
    const int t0  = blockIdx.x * TILE;
    const int tid = threadIdx.x;            // 0..511
    const int lane = tid & 63, wvid = tid >> 6;   // 8 waves
    const int r_lo = lane & 15, kb = lane >> 4;
    const size_t rowbase = (size_t)b*NT;
    const bool interior = (t0 >= 3) && (t0 + HALO - 3 <= NT);  // halo fully in-range
    __shared__ __align__(16) unsigned short s_a[32*YST];   // y (32 rows) -> uc (16xUST)
    __shared__ __align__(16) unsigned short s_u[HALO*UST]; // u (22 rows) -> v (16 rows)

    // --- P0: h rows t0-3..t0+18 (load or inline-compute), LN -> s_a ---
    {
        const int r  = tid >> 4;            // 0..31; rows >= HALO skipped
        const int c0 = (tid & 15) * 16;
        if (r < HALO) {
            const int t  = t0 - 3 + r;
            const bool vld = interior || ((t >= 0) && (t < NT));
            float vals[16];
            if (vld) {
                if (FIRST) {
                    float xv = x[rowbase + t];
                    const float4* wp = reinterpret_cast<const float4*>(w_in + c0);
                    const float4* bp = reinterpret_cast<const float4*>(b_in + c0);
                    const float4* pp = reinterpret_cast<const float4*>(pos + t*ND + c0);
                    #pragma unroll
                    for (int j = 0; j < 4; ++j) {
                        float4 w = wp[j], bb = bp[j], p = pp[j];
                        vals[4*j+0] = fmaf(xv, w.x, bb.x + p.x);
                        vals[4*j+1] = fmaf(xv, w.y, bb.y + p.y);
                        vals[4*j+2] = fmaf(xv, w.z, bb.z + p.z);
                        vals[4*j+3] = fmaf(xv, w.w, bb.w + p.w);
                    }
                } else {
                    const float4* hp = reinterpret_cast<const float4*>(
                        hin + (rowbase + t)*ND + c0);
                    #pragma unroll
                    for (int j = 0; j < 4; ++j) {
                        float4 f = hp[j];
                        vals[4*j+0]=f.x; vals[4*j+1]=f.y; vals[4*j+2]=f.z; vals[4*j+3]=f.w;
                    }
                }
            } else {
                #pragma unroll
                for (int j = 0; j < 16; ++j) vals[j] = 0.0f;
            }
            f32x2 sv = (f32x2){0.f, 0.f}, s2v = (f32x2){0.f, 0.f};
            #pragma unroll
            for (int j = 0; j < 8; ++j) {
                f32x2 v = (f32x2){vals[2*j], vals[2*j+1]};
                sv += v; s2v += v*v;
            }
            float s = sv[0] + sv[1], s2 = s2v[0] + s2v[1];
            #pragma unroll
            for (int off = 1; off < 16; off <<= 1) {
                s  += __shfl_xor(s, off);
                s2 += __shfl_xor(s2, off);
            }
            float mu  = s * (1.0f/ND);
            float var = s2 * (1.0f/ND) - mu*mu;
            float rs  = rsqrtf(var + EPSF);
            if (!vld) rs = 0.0f;           // zero rows stay zero
            #pragma unroll
            for (int jj = 0; jj < 2; ++jj) {
                u32x4 pk;
                #pragma unroll
                for (int q = 0; q < 2; ++q) {
                    const int j = jj*2 + q;
                    float y0 = (vals[4*j+0]-mu)*rs;
                    float y1 = (vals[4*j+1]-mu)*rs;
                    float y2 = (vals[4*j+2]-mu)*rs;
                    float y3 = (vals[4*j+3]-mu)*rs;
                    pk[2*q+0] = f2bf2(y0, y1);
                    pk[2*q+1] = f2bf2(y2, y3);
                }
                *reinterpret_cast<u32x4*>(&s_a[r*YST + c0 + 8*jj]) = pk;
            }
        }
    }
    __syncthreads();

    // --- P1: grouped in-proj. u over halo rows -> s_u; gates (central) -> regs ---
    unsigned int gpk[8];    // gates bf16-packed: [nt*2 + (r>>1)]
    {
        const int rt = wvid >> 2, g = wvid & 3;
        s16x8 a = *reinterpret_cast<const s16x8*>(
            &s_a[(rt*16 + r_lo)*YST + g*32 + kb*8]);
        #pragma unroll
        for (int half = 0; half < 2; ++half) {
            f32x4 acc[4];
            #pragma unroll
            for (int q = 0; q < 4; ++q) {               // bias pre-loaded into C
                const float bia = inb_f[g*128 + (half*4 + q)*16 + r_lo];
                acc[q] = (f32x4){bia, bia, bia, bia};
            }
            #pragma unroll
            for (int q = 0; q < 4; ++q) {
                const int nt = half*4 + q;
                s16x8 bf = *reinterpret_cast<const s16x8*>(
                    inw_b + (size_t)((g*8 + nt)*64 + lane)*8);
                acc[q] = __builtin_amdgcn_mfma_f32_16x16x32_bf16(a, bf, acc[q], 0, 0, 0);
            }
            if (interior) {
                #pragma unroll
                for (int q = 0; q < 4; ++q) {
                    const int nt = half*4 + q;
                    const int ocol = g*128 + nt*16 + r_lo;
                    #pragma unroll
                    for (int r = 0; r < 4; ++r) {
                        const int hr = rt*16 + kb*4 + r;
                        if (hr < HALO) {
                            float tv = acc[q][r];
                            s_u[hr*UST + ocol] = f2bf(tv * sigm(tv));
                        }
                    }
                }
            } else {
                #pragma unroll
                for (int q = 0; q < 4; ++q) {
                    const int nt = half*4 + q;
                    const int ocol = g*128 + nt*16 + r_lo;
                    #pragma unroll
                    for (int r = 0; r < 4; ++r) {
                        const int hr = rt*16 + kb*4 + r;
                        if (hr < HALO) {
                            const int t = t0 - 3 + hr;
                            unsigned short val = 0;
                            if (t >= 0 && t < NT) {
                                float tv = acc[q][r];
                                val = f2bf(tv * sigm(tv));
                            }
                            s_u[hr*UST + ocol] = val;
                        }
                    }
                }
            }
        }
        // gate-part: central rows (y rows 3..18); wave owns gate cols wvid*64..+63.
        s16x8 ag = *reinterpret_cast<const s16x8*>(
            &s_a[(3 + r_lo)*YST + 128 + (wvid >> 1)*32 + kb*8]);
        f32x4 gacc[4];
        #pragma unroll
        for (int nt = 0; nt < 4; ++nt) {               // bias pre-loaded into C
            const float bia = inb_f[512 + wvid*64 + nt*16 + r_lo];
            gacc[nt] = (f32x4){bia, bia, bia, bia};
        }
        #pragma unroll
        for (int nt = 0; nt < 4; ++nt) {
            const int instr = (4 + (wvid >> 1))*8 + (wvid & 1)*4 + nt;
            s16x8 bf = *reinterpret_cast<const s16x8*>(
                inw_b + (size_t)(instr*64 + lane)*8);
            gacc[nt] = __builtin_amdgcn_mfma_f32_16x16x32_bf16(ag, bf, gacc[nt], 0, 0, 0);
        }
        #pragma unroll
        for (int nt = 0; nt < 4; ++nt) {
            #pragma unroll
            for (int rp = 0; rp < 2; ++rp) {
                float s0 = sigm(gacc[nt][2*rp]);
                float s1 = sigm(gacc[nt][2*rp+1]);
                gpk[nt*2 + rp] = f2bf2(s0, s1);
            }
        }
    }
    __syncthreads();

    // --- P2: symmetric conv (4 taps); thread owns CHANNEL PAIR + row half ---
    // thread t: channels (2*(t&255), +1); output rows half*8..half*8+7 (half=t>>8).
    // u32 packed LDS ops: 14 reads + 8 writes (vs 28+16 u16).
    {
        const int half = tid >> 8;          // 0 or 1
        const int c0   = (tid & 255) * 2;
        const int rb   = half * 8;          // first output row
        const float4 cwa = *reinterpret_cast<const float4*>(dws + c0*4);
        const float4 cwb = *reinterpret_cast<const float4*>(dws + c0*4 + 4);
        const f32x2 t0w = (f32x2){cwa.x, cwb.x};
        const f32x2 t1w = (f32x2){cwa.y, cwb.y};
        const f32x2 t2w = (f32x2){cwa.z, cwb.z};
        const f32x2 t3w = (f32x2){cwa.w, cwb.w};
        f32x2 w0 = upk2(*reinterpret_cast<const unsigned int*>(&s_u[(rb+0)*UST + c0]));
        f32x2 w1 = upk2(*reinterpret_cast<const unsigned int*>(&s_u[(rb+1)*UST + c0]));
        f32x2 w2 = upk2(*reinterpret_cast<const unsigned int*>(&s_u[(rb+2)*UST + c0]));
        f32x2 w3 = upk2(*reinterpret_cast<const unsigned int*>(&s_u[(rb+3)*UST + c0]));
        f32x2 w4 = upk2(*reinterpret_cast<const unsigned int*>(&s_u[(rb+4)*UST + c0]));
        f32x2 w5 = upk2(*reinterpret_cast<const unsigned int*>(&s_u[(rb+5)*UST + c0]));
        #pragma unroll
        for (int cr = 0; cr < 8; ++cr) {
            f32x2 w6 = upk2(*reinterpret_cast<const unsigned int*>(
                &s_u[(rb + cr + 6)*UST + c0]));
            f32x2 s = t3w * w3;
            s += t0w * (w0 + w6);
            s += t1w * (w1 + w5);
            s += t2w * (w2 + w4);
            *reinterpret_cast<unsigned int*>(&s_a[(rb + cr)*UST + c0]) =
                f2bf2(s[0], s[1]);
            w0 = w1; w1 = w2; w2 = w3; w3 = w4; w4 = w5; w5 = w6;
        }
    }
    __syncthreads();

    // --- P3: grouped mix (K=64) + in-reg gates -> v (s_u rows 0..15) ---
    {
        const int g = wvid;
        s16x8 a0 = *reinterpret_cast<const s16x8*>(&s_a[r_lo*UST + g*64 + kb*8]);
        s16x8 a1 = *reinterpret_cast<const s16x8*>(&s_a[r_lo*UST + g*64 + 32 + kb*8]);
        f32x4 acc[4];
        #pragma unroll
        for (int nt = 0; nt < 4; ++nt) {               // bias pre-loaded into C
            const float bia = mixb[g*64 + nt*16 + r_lo];
            acc[nt] = (f32x4){bia, bia, bia, bia};
        }
        #pragma unroll
        for (int nt = 0; nt < 4; ++nt) {
            s16x8 b0 = *reinterpret_cast<const s16x8*>(
                mixw_b + (size_t)(((g*4 + nt)*2 + 0)*64 + lane)*8);
            acc[nt] = __builtin_amdgcn_mfma_f32_16x16x32_bf16(a0, b0, acc[nt], 0, 0, 0);
        }
        #pragma unroll
        for (int nt = 0; nt < 4; ++nt) {
            s16x8 b1 = *reinterpret_cast<const s16x8*>(
                mixw_b + (size_t)(((g*4 + nt)*2 + 1)*64 + lane)*8);
            acc[nt] = __builtin_amdgcn_mfma_f32_16x16x32_bf16(a1, b1, acc[nt], 0, 0, 0);
        }
        #pragma unroll
        for (int nt = 0; nt < 4; ++nt) {
            const int ocol = g*64 + nt*16 + r_lo;
            #pragma unroll
            for (int r = 0; r < 4; ++r) {
                const int cr = kb*4 + r;
                unsigned short gu = (unsigned short)
                    ((gpk[nt*2 + (r >> 1)] >> ((r & 1)*16)) & 0xffffu);
                s_u[cr*UST + ocol] = f2bf(acc[nt][r] * bf2f(gu));
            }
        }
    }
    __syncthreads();

    // --- P4: residual (load or recompute) + out-proj [+ final LN] -> hout ---
    float hres[2][4];
    #pragma unroll
    for (int c4 = 0; c4 < 2; ++c4) {
        const int d = wvid*32 + c4*16 + r_lo;
        #pragma unroll
        for (int r = 0; r < 4; ++r) {
            const int t = t0 + kb*4 + r;
            if (FIRST) {
                hres[c4][r] = (t < NT)
                    ? fmaf(x[rowbase + t], w_in[d], b_in[d] + pos[t*ND + d]) : 0.0f;
            } else {
                hres[c4][r] = (t < NT) ? hin[(rowbase + t)*ND + d] : 0.0f;
            }
        }
    }
    f32x4 acc4[2];
    #pragma unroll
    for (int c4 = 0; c4 < 2; ++c4) {                   // out-bias pre-loaded into C
        const float ob = outb[wvid*32 + c4*16 + r_lo];
        acc4[c4] = (f32x4){ob, ob, ob, ob};
    }
    #pragma unroll
    for (int ks = 0; ks < 16; ++ks) {
        s16x8 a = *reinterpret_cast<const s16x8*>(&s_u[r_lo*UST + ks*32 + kb*8]);
        #pragma unroll
        for (int c4 = 0; c4 < 2; ++c4) {
            const int c4t = wvid*2 + c4;
            s16x8 bf = *reinterpret_cast<const s16x8*>(
                outw_b + (size_t)((ks*16 + c4t)*64 + lane)*8);
            acc4[c4] = __builtin_amdgcn_mfma_f32_16x16x32_bf16(a, bf, acc4[c4], 0, 0, 0);
        }
    }
    if (!LAST) {
        #pragma unroll
        for (int c4 = 0; c4 < 2; ++c4) {
            const int d = wvid*32 + c4*16 + r_lo;
            #pragma unroll
            for (int r = 0; r < 4; ++r) {
                const int cr = kb*4 + r;
                const int t = t0 + cr;
                if (t < NT)
                    hout[(rowbase + t)*ND + d] = hres[c4][r] + acc4[c4][r];
            }
        }
    } else {
        // final-LN fusion: block owns full 256-col rows.
        float outv[2][4];
        #pragma unroll
        for (int c4 = 0; c4 < 2; ++c4) {
            #pragma unroll
            for (int r = 0; r < 4; ++r)
                outv[c4][r] = hres[c4][r] + acc4[c4][r];
        }
        // per-row partial sums: reduce over r_lo (16 lanes) x c4 (2)
        f32x2* part = reinterpret_cast<f32x2*>(s_a);   // [16 rows][8 waves]
        #pragma unroll
        for (int r = 0; r < 4; ++r) {
            float s  = outv[0][r] + outv[1][r];
            float s2 = outv[0][r]*outv[0][r] + outv[1][r]*outv[1][r];
            #pragma unroll
            for (int off = 1; off < 16; off <<= 1) {   // within 16-lane group
                s  += __shfl_xor(s, off);
                s2 += __shfl_xor(s2, off);
            }
            if (r_lo == 0) part[(kb*4 + r)*8 + wvid] = (f32x2){s, s2};
        }
        __syncthreads();
        #pragma unroll
        for (int c4 = 0; c4 < 2; ++c4) {
            const int d = wvid*32 + c4*16 + r_lo;
            const float og = olng[d], obb = olnb[d];
            #pragma unroll
            for (int r = 0; r < 4; ++r) {
                const int cr = kb*4 + r;
                const int t = t0 + cr;
                if (t < NT) {
                    f32x2 tot = (f32x2){0.f, 0.f};
                    #pragma unroll
                    for (int w = 0; w < 8; ++w) tot += part[cr*8 + w];
                    float mu  = tot[0] * (1.0f/ND);
                    float var = tot[1] * (1.0f/ND) - mu*mu;
                    float rs  = rsqrtf(var + EPSF);
                    hout[(rowbase + t)*ND + d] =
                        (outv[c4][r] - mu)*rs*og + obb;
                }
            }
        }
    }
}

extern "C" void kernel_launch(void* const* d_in, const int* in_sizes, int n_in,
                              void* d_out, int out_size, void* d_ws, size_t ws_size,
                              hipStream_t stream)
{
    const float* x    = (const float*)d_in[0];
    const float* w_in = (const float*)d_in[1];
    const float* b_in = (const float*)d_in[2];
    const float* pos  = (const float*)d_in[3];
    const float* ln_g = (const float*)d_in[4];
    const float* ln_b = (const float*)d_in[5];
    const float* inw  = (const float*)d_in[6];
    const float* inb  = (const float*)d_in[7];
    const float* dww  = (const float*)d_in[8];
    const float* mixw = (const float*)d_in[9];
    const float* mixb = (const float*)d_in[10];
    const float* outw = (const float*)d_in[11];
    const float* outb = (const float*)d_in[12];
    const float* olng = (const float*)d_in[13];
    const float* olnb = (const float*)d_in[14];

    float* hA = (float*)d_out;                         // final result here
    float* hB = (float*)d_ws;
    unsigned short* outw_b = (unsigned short*)((char*)d_ws + (size_t)NPOS*ND*4);
    unsigned short* mixw_b = outw_b + 524288;          // L*D*H
    unsigned short* inw_b  = mixw_b + 131072;          // L*H*64 ; then L*1024*32
    float*          dws    = (float*)(inw_b + 131072); // L*512*4 symmetrized conv wts
    float*          inb_f  = dws + 8192;               // L*1024 folded in-proj bias

    k_prep<<<3120, 256, 0, stream>>>(outw, mixw, inw, dww, ln_g, ln_b, inb,
                                     outw_b, mixw_b, inw_b, dws, inb_f);
    // layer 0: FIRST (h inline from x/w_in/b_in/pos) -> hB
    kL2<true,false><<<dim3(18, NB), 512, 0, stream>>>(hA, hB,
        inw_b, inb_f, dws, mixw_b, mixb, outw_b, outb,
        x, w_in, b_in, pos, olng, olnb);
    // layer 1: hB -> hA
    kL2<false,false><<<dim3(18, NB), 512, 0, stream>>>(hB, hA,
        inw_b + 32768, inb_f + NHH, dws + 2048,
        mixw_b + 32768, mixb + NH, outw_b + 131072, outb + ND,
        x, w_in, b_in, pos, olng, olnb);
    // layer 2: hA -> hB
    kL2<false,false><<<dim3(18, NB), 512, 0, stream>>>(hA, hB,
        inw_b + 2*32768, inb_f + 2*NHH, dws + 2*2048,
        mixw_b + 2*32768, mixb + 2*NH, outw_b + 2*131072, outb + 2*ND,
        x, w_in, b_in, pos, olng, olnb);
    // layer 3: LAST (final LN fused) hB -> hA (= d_out)
    kL2<false,true><<<dim3(18, NB), 512, 0, stream>>>(hB, hA,
        inw_b + 3*32768, inb_f + 3*NHH, dws + 3*2048,
        mixw_b + 3*32768, mixb + 3*NH, outw_b + 3*131072, outb + 3*ND,
        x, w_in, b_in, pos, olng, olnb);
}